// Round 8
// baseline (100.758 us; speedup 1.0000x reference)
//
#include <hip/hip_runtime.h>
#include <hip/hip_bf16.h>

#define NTOT 8192
#define NBSZ 4096
#define DDIM 256
#define NPANEL 32
#define PANEL 256
#define TILE_COLS 32
#define NT (PANEL / TILE_COLS)
#define NCLASS 100

#define INV_T 14.285714285714286f
#define EPI_T 1.4285714285714286f
// base-2 folded: exp(logit) = exp2(dot*K1 + same*BIASS)
#define K1 20.609929155556076f      /* INV_T * log2(e) */
#define BIASS -2.0609929155556078f  /* -EPI_T * log2(e) */

typedef __attribute__((ext_vector_type(8))) __bf16 bf16x8;
typedef __attribute__((ext_vector_type(4))) float f32x4;

__device__ __forceinline__ unsigned short f2bf(float x) {
    union { float f; unsigned int u; } a; a.f = x;
    unsigned int r = a.u + 0x7fffu + ((a.u >> 16) & 1u);
    return (unsigned short)(r >> 16);
}

// K1: build bf16 contrast matrix B[8192][256] (view-major) + tiled labels; zero out[0].
__global__ __launch_bounds__(256) void prep_kernel(const float* __restrict__ feat,
                                                   const int* __restrict__ labels,
                                                   unsigned short* __restrict__ Bg,
                                                   int* __restrict__ labT,
                                                   float* __restrict__ out) {
    const int g = blockIdx.x * 256 + threadIdx.x;   // 8192 rows x 64 lanes
    const int row = g >> 6, t = g & 63;
    const int v = row >> 12, b = row & (NBSZ - 1);
    const float* src = feat + (size_t)(b * 2 + v) * DDIM + t * 4;
    f32x4 val = *(const f32x4*)src;
    ushort4 o;
    o.x = f2bf(val[0]); o.y = f2bf(val[1]); o.z = f2bf(val[2]); o.w = f2bf(val[3]);
    *(ushort4*)(Bg + (size_t)row * DDIM + t * 4) = o;
    if (t == 0) labT[row] = labels[b];
    if (g == 0) out[0] = 0.f;
}

// DMA one 32x256 bf16 tile into LDS (linear dest, source pre-swizzled so the
// read-side XOR sees conflict-free layout). 4 x 16B per thread.
__device__ __forceinline__ void stage_tile(const unsigned short* __restrict__ Bg,
                                           unsigned short* buf, int colBase, int tid) {
    #pragma unroll
    for (int it = 0; it < 4; ++it) {
        int c = it * 256 + tid;          // 16B-chunk index, 0..1023
        int brow = c >> 5, bc = c & 31;
        int sc = bc ^ (brow & 7);        // inverse swizzle on SOURCE
        const unsigned short* src = Bg + (size_t)(colBase + brow) * DDIM + sc * 8;
        __builtin_amdgcn_global_load_lds(
            (const __attribute__((address_space(1))) void*)src,
            (__attribute__((address_space(3))) void*)(buf + (size_t)c * 8),
            16, 0, 0);
    }
}

// K2: SYMMETRIC Gram + fused exp/pos sums. Upper-triangle 256x256 tile pairs:
// grid = 528 blocks; block (p,s) p<=s contributes row-sums (panel p, slot s)
// and, for p<s, col-sums (panel s, slot p). Unique writer per (slot,panel),
// all 32 slots covered for every panel -> non-atomic, no zeroing.
__global__ __launch_bounds__(256, 2) void supcon_main(
    const unsigned short* __restrict__ Bg, const int* __restrict__ labT,
    float* __restrict__ pSe, float* __restrict__ pPd)
{
    __shared__ alignas(16) unsigned short btile[2][TILE_COLS * DDIM];  // 2 x 16 KB
    __shared__ int labc_s[PANEL];                                      // 1 KB
    __shared__ float colSe4[4][PANEL];                                 // 4 KB
    __shared__ float colPd4[4][PANEL];                                 // 4 KB

    const int tid = threadIdx.x;
    const int wid = tid >> 6;
    const int lane = tid & 63;
    const int q = lane >> 4;
    const int r16 = lane & 15;

    // decode upper-triangle pair (p,s) from linear block id
    int k = blockIdx.x, p = 0;
    while (k >= NPANEL - p) { k -= NPANEL - p; ++p; }
    const int s = p + k;
    const bool isDiag = (p == s);

    const int rowBase = p * PANEL + wid * 64;   // wave owns 64 rows of panel p
    const int colPanel = s * PANEL;

    labc_s[tid] = labT[colPanel + tid];

    // A fragments: 64 rows x K=256 in registers (128 VGPR).
    bf16x8 afr[4][8];
    #pragma unroll
    for (int m = 0; m < 4; ++m) {
        const unsigned short* ap = Bg + (size_t)(rowBase + m * 16 + r16) * DDIM + q * 8;
        #pragma unroll
        for (int ks = 0; ks < 8; ++ks)
            afr[m][ks] = *(const bf16x8*)(ap + ks * 32);
    }
    int labrow[4][4];
    #pragma unroll
    for (int m = 0; m < 4; ++m)
        #pragma unroll
        for (int r = 0; r < 4; ++r)
            labrow[m][r] = labT[rowBase + m * 16 + q * 4 + r];

    float se[4][4], pd[4][4];
    #pragma unroll
    for (int m = 0; m < 4; ++m)
        #pragma unroll
        for (int r = 0; r < 4; ++r) { se[m][r] = 0.f; pd[m][r] = 0.f; }

    stage_tile(Bg, btile[0], colPanel, tid);
    __syncthreads();   // drains vmcnt -> tile 0 ready

    for (int tile = 0; tile < NT; ++tile) {
        if (tile + 1 < NT)
            stage_tile(Bg, btile[(tile + 1) & 1], colPanel + (tile + 1) * TILE_COLS, tid);

        const unsigned short* bt = btile[tile & 1];
        f32x4 acc[4][2];
        #pragma unroll
        for (int m = 0; m < 4; ++m) { acc[m][0] = (f32x4)0.f; acc[m][1] = (f32x4)0.f; }

        __builtin_amdgcn_s_setprio(1);
        #pragma unroll
        for (int ks = 0; ks < 8; ++ks) {
            const int cx = (ks * 4 + q) ^ (r16 & 7);
            bf16x8 bq0 = *(const bf16x8*)(bt + r16 * DDIM + cx * 8);
            bf16x8 bq1 = *(const bf16x8*)(bt + (16 + r16) * DDIM + cx * 8);
            #pragma unroll
            for (int m = 0; m < 4; ++m) {
                acc[m][0] = __builtin_amdgcn_mfma_f32_16x16x32_bf16(afr[m][ks], bq0, acc[m][0], 0, 0, 0);
                acc[m][1] = __builtin_amdgcn_mfma_f32_16x16x32_bf16(afr[m][ks], bq1, acc[m][1], 0, 0, 0);
            }
        }
        __builtin_amdgcn_s_setprio(0);

        const int colBase = colPanel + tile * TILE_COLS;
        const int lc0 = labc_s[tile * TILE_COLS + r16];
        const int lc1 = labc_s[tile * TILE_COLS + 16 + r16];
        float cse0 = 0.f, cse1 = 0.f, cpd0 = 0.f, cpd1 = 0.f;
        const bool diagT = isDiag && ((unsigned)(colBase - rowBase) < 64u);
        if (!diagT) {
            #pragma unroll
            for (int n = 0; n < 2; ++n) {
                const int lc = n ? lc1 : lc0;
                #pragma unroll
                for (int m = 0; m < 4; ++m)
                    #pragma unroll
                    for (int r = 0; r < 4; ++r) {
                        const bool same = (lc == labrow[m][r]);
                        float a = acc[m][n][r];
                        float e = __builtin_amdgcn_exp2f(fmaf(a, K1, same ? BIASS : 0.f));
                        float v = same ? a : 0.f;
                        se[m][r] += e; pd[m][r] += v;
                        if (n == 0) { cse0 += e; cpd0 += v; }
                        else        { cse1 += e; cpd1 += v; }
                    }
            }
        } else {
            #pragma unroll
            for (int n = 0; n < 2; ++n) {
                const int lc = n ? lc1 : lc0;
                const int gcol = colBase + n * 16 + r16;
                #pragma unroll
                for (int m = 0; m < 4; ++m)
                    #pragma unroll
                    for (int r = 0; r < 4; ++r) {
                        const int grow = rowBase + m * 16 + q * 4 + r;
                        const bool same = (lc == labrow[m][r]);
                        const bool keep = (grow != gcol);
                        float a = acc[m][n][r];
                        float e = __builtin_amdgcn_exp2f(fmaf(a, K1, same ? BIASS : 0.f));
                        e = keep ? e : 0.f;
                        float v = (same && keep) ? a : 0.f;
                        se[m][r] += e; pd[m][r] += v;
                    }
            }
        }

        if (!isDiag) {
            // reduce col partials across the 4 q-groups (lane bits 4,5)
            cse0 += __shfl_xor(cse0, 16); cse0 += __shfl_xor(cse0, 32);
            cse1 += __shfl_xor(cse1, 16); cse1 += __shfl_xor(cse1, 32);
            cpd0 += __shfl_xor(cpd0, 16); cpd0 += __shfl_xor(cpd0, 32);
            cpd1 += __shfl_xor(cpd1, 16); cpd1 += __shfl_xor(cpd1, 32);
            if (q == 0) {
                colSe4[wid][tile * TILE_COLS + r16]      = cse0;
                colSe4[wid][tile * TILE_COLS + 16 + r16] = cse1;
                colPd4[wid][tile * TILE_COLS + r16]      = cpd0;
                colPd4[wid][tile * TILE_COLS + 16 + r16] = cpd1;
            }
        }
        __syncthreads();   // drains DMA (next tile ready) + LDS reads/writes done
    }

    // row-side: merge the 16 lanes (r16 bits) sharing each row, write slot s
    #pragma unroll
    for (int mask = 1; mask <= 8; mask <<= 1)
        #pragma unroll
        for (int m = 0; m < 4; ++m)
            #pragma unroll
            for (int r = 0; r < 4; ++r) {
                se[m][r] += __shfl_xor(se[m][r], mask);
                pd[m][r] += __shfl_xor(pd[m][r], mask);
            }
    if (r16 == 0) {
        #pragma unroll
        for (int m = 0; m < 4; ++m) {
            const size_t o = (size_t)s * NTOT + rowBase + m * 16 + q * 4;
            f32x4 vs, vp;
            #pragma unroll
            for (int r = 0; r < 4; ++r) { vs[r] = se[m][r]; vp[r] = pd[m][r]; }
            *(f32x4*)(pSe + o) = vs;
            *(f32x4*)(pPd + o) = vp;
        }
    }

    // col-side: combine 4 waves' partials, write panel s at slot p
    if (!isDiag) {
        const float a0 = colSe4[0][tid] + colSe4[1][tid] + colSe4[2][tid] + colSe4[3][tid];
        const float a1 = colPd4[0][tid] + colPd4[1][tid] + colPd4[2][tid] + colPd4[3][tid];
        const size_t o = (size_t)p * NTOT + colPanel + tid;
        pSe[o] = a0;
        pPd[o] = a1;
    }
}

// K3: per-row loss (hist + 32-slot sums) + block partial + atomic out. 32 x 256.
__global__ __launch_bounds__(256) void finalize_kernel(
    const int* __restrict__ labT, const float* __restrict__ pSe,
    const float* __restrict__ pPd, float* __restrict__ out)
{
    __shared__ int hist[NCLASS];
    const int t = threadIdx.x;
    if (t < NCLASS) hist[t] = 0;
    __syncthreads();
    #pragma unroll
    for (int i = 0; i < NTOT / 256; ++i)
        atomicAdd(&hist[labT[i * 256 + t]], 1);
    __syncthreads();

    const int row = blockIdx.x * 256 + t;
    const int lab = labT[row];
    float se = 0.f, pdv = 0.f;
    #pragma unroll
    for (int k = 0; k < NPANEL; ++k) {
        se  += pSe[(size_t)k * NTOT + row];
        pdv += pPd[(size_t)k * NTOT + row];
    }
    const float pc = (float)(hist[lab] - 1);
    float loss = EPI_T + __logf(se) - INV_T * pdv / pc;

    #pragma unroll
    for (int mask = 1; mask < 64; mask <<= 1) loss += __shfl_xor(loss, mask);
    __shared__ float red[4];
    if ((t & 63) == 0) red[t >> 6] = loss;
    __syncthreads();
    if (t == 0)
        atomicAdd(out, (red[0] + red[1] + red[2] + red[3]) * (1.f / (float)NTOT));
}

extern "C" void kernel_launch(void* const* d_in, const int* in_sizes, int n_in,
                              void* d_out, int out_size, void* d_ws, size_t ws_size,
                              hipStream_t stream) {
    const float* feat = (const float*)d_in[0];
    const int* labels = (const int*)d_in[1];
    float* out = (float*)d_out;

    char* ws = (char*)d_ws;
    unsigned short* Bg = (unsigned short*)ws;                        // 4 MB
    int* labT = (int*)(ws + (4u << 20));                             // 32 KB
    float* pSe = (float*)(ws + (4u << 20) + (64u << 10));            // 1 MB
    float* pPd = (float*)(ws + (5u << 20) + (64u << 10));            // 1 MB

    prep_kernel<<<2048, 256, 0, stream>>>(feat, labels, Bg, labT, out);
    supcon_main<<<NPANEL * (NPANEL + 1) / 2, 256, 0, stream>>>(Bg, labT, pSe, pPd);
    finalize_kernel<<<32, 256, 0, stream>>>(labT, pSe, pPd, out);
}